// Round 1
// baseline (1577.372 us; speedup 1.0000x reference)
//
#include <hip/hip_runtime.h>
#include <math.h>

#define TOK    4096
#define DIM    1024
#define NHEAD  1002
#define NSHORT 1000
#define C0     9000
#define K0     256
#define C1     40257
#define K1     64
#define SPLITS0 4
#define SPLITS1 8
#define PSTRIDE 8

// ---------------- zero counters ----------------
__global__ void zero_kernel(int* cnt) {
    if (threadIdx.x < 2) cnt[threadIdx.x] = 0;
}

// ---------------- classify targets into cluster lists ----------------
__global__ __launch_bounds__(256) void classify_kernel(
    const int* __restrict__ target, int* __restrict__ cnt,
    int* __restrict__ l0, int* __restrict__ l1)
{
    int t = blockIdx.x * 256 + threadIdx.x;
    if (t >= TOK) return;
    int tg = target[t];
    if (tg >= NSHORT && tg < NSHORT + C0) {
        int i = atomicAdd(&cnt[0], 1); l0[i] = t;
    } else if (tg >= NSHORT + C0) {
        int i = atomicAdd(&cnt[1], 1); l1[i] = t;
    }
}

// ---------------- tiled SGEMM: Y = X @ W^T ----------------
// X: (TOK, DIM) row-major; W: (nrows, DIM) row-major; Y: (TOK, ldY) row-major.
// BM=BN=64, BK=16, 256 threads, 4x4 microtile.
__global__ __launch_bounds__(256) void sgemm_xwT(
    const float* __restrict__ X, const float* __restrict__ W,
    float* __restrict__ Y, int nrows, int ldY)
{
    const int tid = threadIdx.x;
    const int bm = blockIdx.y * 64;
    const int bn = blockIdx.x * 64;
    __shared__ float Xs[16][68];
    __shared__ float Ws[16][68];
    const int lr = tid >> 2;          // 0..63
    const int lc = (tid & 3) << 2;    // 0,4,8,12
    const int tr = tid >> 4;          // 0..15
    const int tc = tid & 15;          // 0..15
    float acc[4][4] = {};
    int wrow = bn + lr;
    if (wrow > nrows - 1) wrow = nrows - 1;   // clamp (stores guarded)
    for (int kk = 0; kk < DIM; kk += 16) {
        float4 xv = *(const float4*)(X + (size_t)(bm + lr) * DIM + kk + lc);
        float4 wv = *(const float4*)(W + (size_t)wrow * DIM + kk + lc);
        Xs[lc + 0][lr] = xv.x; Xs[lc + 1][lr] = xv.y;
        Xs[lc + 2][lr] = xv.z; Xs[lc + 3][lr] = xv.w;
        Ws[lc + 0][lr] = wv.x; Ws[lc + 1][lr] = wv.y;
        Ws[lc + 2][lr] = wv.z; Ws[lc + 3][lr] = wv.w;
        __syncthreads();
        #pragma unroll
        for (int k = 0; k < 16; ++k) {
            float a0 = Xs[k][tr * 4 + 0], a1 = Xs[k][tr * 4 + 1];
            float a2 = Xs[k][tr * 4 + 2], a3 = Xs[k][tr * 4 + 3];
            float b0 = Ws[k][tc * 4 + 0], b1 = Ws[k][tc * 4 + 1];
            float b2 = Ws[k][tc * 4 + 2], b3 = Ws[k][tc * 4 + 3];
            acc[0][0] = fmaf(a0, b0, acc[0][0]); acc[0][1] = fmaf(a0, b1, acc[0][1]);
            acc[0][2] = fmaf(a0, b2, acc[0][2]); acc[0][3] = fmaf(a0, b3, acc[0][3]);
            acc[1][0] = fmaf(a1, b0, acc[1][0]); acc[1][1] = fmaf(a1, b1, acc[1][1]);
            acc[1][2] = fmaf(a1, b2, acc[1][2]); acc[1][3] = fmaf(a1, b3, acc[1][3]);
            acc[2][0] = fmaf(a2, b0, acc[2][0]); acc[2][1] = fmaf(a2, b1, acc[2][1]);
            acc[2][2] = fmaf(a2, b2, acc[2][2]); acc[2][3] = fmaf(a2, b3, acc[2][3]);
            acc[3][0] = fmaf(a3, b0, acc[3][0]); acc[3][1] = fmaf(a3, b1, acc[3][1]);
            acc[3][2] = fmaf(a3, b2, acc[3][2]); acc[3][3] = fmaf(a3, b3, acc[3][3]);
        }
        __syncthreads();
    }
    #pragma unroll
    for (int i = 0; i < 4; ++i) {
        int row = bm + tr * 4 + i;
        #pragma unroll
        for (int j = 0; j < 4; ++j) {
            int col = bn + tc * 4 + j;
            if (col < nrows) Y[(size_t)row * ldY + col] = acc[i][j];
        }
    }
}

// ---------------- per-token head logsumexp ----------------
__global__ __launch_bounds__(256) void head_lse_kernel(
    const float* __restrict__ H, const int* __restrict__ target,
    float* __restrict__ a0, float* __restrict__ a1, float* __restrict__ out)
{
    const int t = blockIdx.x;
    const int tid = threadIdx.x;
    const float* row = H + (size_t)t * DIM;   // stride 1024, 1002 valid
    __shared__ float red[256];
    float m = -1e30f;
    for (int j = tid; j < NHEAD; j += 256) m = fmaxf(m, row[j]);
    red[tid] = m;
    __syncthreads();
    for (int off = 128; off; off >>= 1) {
        if (tid < off) red[tid] = fmaxf(red[tid], red[tid + off]);
        __syncthreads();
    }
    float M = red[0];
    __syncthreads();
    float s = 0.f;
    for (int j = tid; j < NHEAD; j += 256) s += __expf(row[j] - M);
    red[tid] = s;
    __syncthreads();
    for (int off = 128; off; off >>= 1) {
        if (tid < off) red[tid] += red[tid + off];
        __syncthreads();
    }
    if (tid == 0) {
        float lse = M + __logf(red[0]);
        a0[t] = row[1000] - lse;
        a1[t] = row[1001] - lse;
        int tg = target[t];
        if (tg < NSHORT) out[t] = row[tg] - lse;
    }
}

// ---------------- cluster online logsumexp ----------------
// 16 tokens per block, class range split over gridDim.y, 2 classes/thread/iter.
template<int K>
__global__ __launch_bounds__(256) void cluster_lse_kernel(
    const float* __restrict__ XA, const float* __restrict__ Wb,
    int C, int base, const int* __restrict__ list,
    const int* __restrict__ cnt, int ci, const int* __restrict__ target,
    int csize, float* __restrict__ pmax, float* __restrict__ psum,
    float* __restrict__ tgtlog)
{
    constexpr int TT = 16;
    const int n = cnt[ci];
    const int tile = blockIdx.x;
    if (tile * TT >= n) return;
    const int sp = blockIdx.y;
    const int tid = threadIdx.x;
    __shared__ __align__(16) float xas[TT][K];
    __shared__ int tk[TT], tl[TT];
    __shared__ float wm[4][TT], wsum[4][TT];
    if (tid < TT) {
        int i = tile * TT + tid;
        int tok = (i < n) ? list[i] : -1;
        tk[tid] = tok;
        tl[tid] = (tok >= 0) ? (target[tok] - base) : -1;
    }
    __syncthreads();
    for (int idx = tid; idx < TT * K; idx += 256) {
        int t = idx / K, k = idx % K;
        int tok = tk[t];
        xas[t][k] = (tok >= 0) ? XA[(size_t)tok * K + k] : 0.f;
    }
    __syncthreads();

    float m[TT], s[TT];
    #pragma unroll
    for (int t = 0; t < TT; ++t) { m[t] = -1e30f; s[t] = 0.f; }

    const int cbeg = sp * csize;
    const int cend = min(C, cbeg + csize);
    for (int j0 = cbeg + tid * 2; j0 < cend; j0 += 512) {
        const int j1 = j0 + 1;
        const bool h1 = (j1 < cend);
        const float* w0p = Wb + (size_t)j0 * K;
        const float* w1p = w0p + (h1 ? K : 0);
        float acc0[TT] = {}, acc1[TT] = {};
        for (int k = 0; k < K; k += 4) {
            float4 w0 = *(const float4*)(w0p + k);
            float4 w1 = *(const float4*)(w1p + k);
            #pragma unroll
            for (int t = 0; t < TT; ++t) {
                float4 xv = *(const float4*)(&xas[t][k]);   // wave-broadcast
                acc0[t] = fmaf(w0.x, xv.x, fmaf(w0.y, xv.y, fmaf(w0.z, xv.z, fmaf(w0.w, xv.w, acc0[t]))));
                acc1[t] = fmaf(w1.x, xv.x, fmaf(w1.y, xv.y, fmaf(w1.z, xv.z, fmaf(w1.w, xv.w, acc1[t]))));
            }
        }
        #pragma unroll
        for (int t = 0; t < TT; ++t) {
            float v0 = acc0[t];
            if (j0 == tl[t]) tgtlog[tk[t]] = v0;
            if (v0 > m[t]) { s[t] = s[t] * __expf(m[t] - v0) + 1.f; m[t] = v0; }
            else           { s[t] += __expf(v0 - m[t]); }
            if (h1) {
                float v1 = acc1[t];
                if (j1 == tl[t]) tgtlog[tk[t]] = v1;
                if (v1 > m[t]) { s[t] = s[t] * __expf(m[t] - v1) + 1.f; m[t] = v1; }
                else           { s[t] += __expf(v1 - m[t]); }
            }
        }
    }
    // wave-level (m,s) reduction
    const int lane = tid & 63, wv = tid >> 6;
    #pragma unroll
    for (int off = 32; off; off >>= 1) {
        #pragma unroll
        for (int t = 0; t < TT; ++t) {
            float mo = __shfl_xor(m[t], off, 64);
            float so = __shfl_xor(s[t], off, 64);
            float M = fmaxf(m[t], mo);
            s[t] = s[t] * __expf(m[t] - M) + so * __expf(mo - M);
            m[t] = M;
        }
    }
    if (lane == 0) {
        #pragma unroll
        for (int t = 0; t < TT; ++t) { wm[wv][t] = m[t]; wsum[wv][t] = s[t]; }
    }
    __syncthreads();
    if (tid < TT) {
        int t = tid;
        float M = -1e30f, S = 0.f;
        #pragma unroll
        for (int w = 0; w < 4; ++w) {
            float mo = wm[w][t], so = wsum[w][t];
            float Mn = fmaxf(M, mo);
            S = S * __expf(M - Mn) + so * __expf(mo - Mn);
            M = Mn;
        }
        int i = tile * TT + t;
        if (i < n) {
            pmax[(size_t)i * PSTRIDE + sp] = M;
            psum[(size_t)i * PSTRIDE + sp] = S;
        }
    }
}

// ---------------- combine split partials -> output ----------------
__global__ __launch_bounds__(256) void cluster_combine_kernel(
    const int* __restrict__ cnt, int ci, const int* __restrict__ list,
    const float* __restrict__ pmax, const float* __restrict__ psum, int splits,
    const float* __restrict__ tgtlog, const float* __restrict__ ah,
    float* __restrict__ out)
{
    int i = blockIdx.x * 256 + threadIdx.x;
    if (i >= cnt[ci]) return;
    int tok = list[i];
    float M = -1e30f, S = 0.f;
    for (int sp = 0; sp < splits; ++sp) {
        float mo = pmax[(size_t)i * PSTRIDE + sp];
        float so = psum[(size_t)i * PSTRIDE + sp];
        float Mn = fmaxf(M, mo);
        S = S * __expf(M - Mn) + so * __expf(mo - Mn);
        M = Mn;
    }
    out[tok] = tgtlog[tok] - (M + __logf(S)) + ah[tok];
}

// ---------------- loss = -mean(out) ----------------
__global__ __launch_bounds__(256) void loss_kernel(
    const float* __restrict__ out, float* __restrict__ loss)
{
    __shared__ float red[256];
    int tid = threadIdx.x;
    float s = 0.f;
    for (int j = tid; j < TOK; j += 256) s += out[j];
    red[tid] = s;
    __syncthreads();
    for (int off = 128; off; off >>= 1) {
        if (tid < off) red[tid] += red[tid + off];
        __syncthreads();
    }
    if (tid == 0) loss[0] = -red[0] / (float)TOK;
}

extern "C" void kernel_launch(void* const* d_in, const int* in_sizes, int n_in,
                              void* d_out, int out_size, void* d_ws, size_t ws_size,
                              hipStream_t stream) {
    const float* x      = (const float*)d_in[0];
    const int*   target = (const int*)  d_in[1];
    const float* W_head = (const float*)d_in[2];
    const float* W0a    = (const float*)d_in[3];
    const float* W0b    = (const float*)d_in[4];
    const float* W1a    = (const float*)d_in[5];
    const float* W1b    = (const float*)d_in[6];
    float* out  = (float*)d_out;     // 4096 target log-probs
    float* loss = out + TOK;         // +1 scalar

    // workspace layout (floats)
    float* ws     = (float*)d_ws;
    float* H      = ws;                            // TOK*1024 (1002 valid cols)
    float* XA0    = H + (size_t)TOK * 1024;        // TOK*256
    float* XA1    = XA0 + (size_t)TOK * K0;        // TOK*64
    float* a0     = XA1 + (size_t)TOK * K1;        // TOK
    float* a1     = a0 + TOK;                      // TOK
    float* tgtlog = a1 + TOK;                      // TOK
    float* pmax0  = tgtlog + TOK;                  // TOK*8
    float* psum0  = pmax0 + (size_t)TOK * PSTRIDE;
    float* pmax1  = psum0 + (size_t)TOK * PSTRIDE;
    float* psum1  = pmax1 + (size_t)TOK * PSTRIDE;
    int*   cnt    = (int*)(psum1 + (size_t)TOK * PSTRIDE);
    int*   l0     = cnt + 8;
    int*   l1     = l0 + TOK;

    zero_kernel<<<1, 64, 0, stream>>>(cnt);
    classify_kernel<<<TOK / 256, 256, 0, stream>>>(target, cnt, l0, l1);

    // H = x @ W_head^T   (4096 x 1002, ld 1024)
    sgemm_xwT<<<dim3((NHEAD + 63) / 64, TOK / 64), 256, 0, stream>>>(x, W_head, H, NHEAD, 1024);
    // XA0 = x @ W0a^T    (4096 x 256)
    sgemm_xwT<<<dim3(K0 / 64, TOK / 64), 256, 0, stream>>>(x, W0a, XA0, K0, K0);
    // XA1 = x @ W1a^T    (4096 x 64)
    sgemm_xwT<<<dim3(K1 / 64, TOK / 64), 256, 0, stream>>>(x, W1a, XA1, K1, K1);

    head_lse_kernel<<<TOK, 256, 0, stream>>>(H, target, a0, a1, out);

    cluster_lse_kernel<K0><<<dim3(TOK / 16, SPLITS0), 256, 0, stream>>>(
        XA0, W0b, C0, NSHORT, l0, cnt, 0, target,
        (C0 + SPLITS0 - 1) / SPLITS0, pmax0, psum0, tgtlog);
    cluster_lse_kernel<K1><<<dim3(TOK / 16, SPLITS1), 256, 0, stream>>>(
        XA1, W1b, C1, NSHORT + C0, l1, cnt, 1, target,
        (C1 + SPLITS1 - 1) / SPLITS1, pmax1, psum1, tgtlog);

    cluster_combine_kernel<<<TOK / 256, 256, 0, stream>>>(cnt, 0, l0, pmax0, psum0, SPLITS0, tgtlog, a0, out);
    cluster_combine_kernel<<<TOK / 256, 256, 0, stream>>>(cnt, 1, l1, pmax1, psum1, SPLITS1, tgtlog, a1, out);

    loss_kernel<<<1, 256, 0, stream>>>(out, loss);
}

// Round 2
// 661.729 us; speedup vs baseline: 2.3837x; 2.3837x over previous
//
#include <hip/hip_runtime.h>
#include <math.h>

#define TOK    4096
#define DIM    1024
#define NHEAD  1002
#define NSHORT 1000
#define C0     9000
#define K0     256
#define C1     40257
#define K1     64
#define SP0    16
#define SP1    32
#define PS     32    // psum row stride (>= max splits)

typedef __attribute__((ext_vector_type(8))) short short8;
typedef __attribute__((ext_vector_type(4))) float float4v;

// ---------------- zero counters ----------------
__global__ void zero_kernel(int* cnt) {
    if (threadIdx.x < 2) cnt[threadIdx.x] = 0;
}

// ---------------- classify targets into cluster lists ----------------
__global__ __launch_bounds__(256) void classify_kernel(
    const int* __restrict__ target, int* __restrict__ cnt,
    int* __restrict__ l0, int* __restrict__ l1)
{
    int t = blockIdx.x * 256 + threadIdx.x;
    if (t >= TOK) return;
    int tg = target[t];
    if (tg >= NSHORT && tg < NSHORT + C0) {
        int i = atomicAdd(&cnt[0], 1); l0[i] = t;
    } else if (tg >= NSHORT + C0) {
        int i = atomicAdd(&cnt[1], 1); l1[i] = t;
    }
}

// ---------------- fp32 -> bf16 (RNE) cast ----------------
__global__ __launch_bounds__(256) void cast_bf16_kernel(
    const float* __restrict__ src, unsigned short* __restrict__ dst, int n)
{
    int i = blockIdx.x * 256 + threadIdx.x;
    if (i < n) {
        unsigned int u = __float_as_uint(src[i]);
        unsigned int r = (u + 0x7FFFu + ((u >> 16) & 1u)) >> 16;
        dst[i] = (unsigned short)r;
    }
}

// ---------------- tiled fp32 SGEMM: Y = X @ W^T ----------------
__global__ __launch_bounds__(256) void sgemm_xwT(
    const float* __restrict__ X, const float* __restrict__ W,
    float* __restrict__ Y, int nrows, int ldY)
{
    const int tid = threadIdx.x;
    const int bm = blockIdx.y * 64;
    const int bn = blockIdx.x * 64;
    __shared__ float Xs[16][68];
    __shared__ float Ws[16][68];
    const int lr = tid >> 2;
    const int lc = (tid & 3) << 2;
    const int tr = tid >> 4;
    const int tc = tid & 15;
    float acc[4][4] = {};
    int wrow = bn + lr;
    if (wrow > nrows - 1) wrow = nrows - 1;
    for (int kk = 0; kk < DIM; kk += 16) {
        float4 xv = *(const float4*)(X + (size_t)(bm + lr) * DIM + kk + lc);
        float4 wv = *(const float4*)(W + (size_t)wrow * DIM + kk + lc);
        Xs[lc + 0][lr] = xv.x; Xs[lc + 1][lr] = xv.y;
        Xs[lc + 2][lr] = xv.z; Xs[lc + 3][lr] = xv.w;
        Ws[lc + 0][lr] = wv.x; Ws[lc + 1][lr] = wv.y;
        Ws[lc + 2][lr] = wv.z; Ws[lc + 3][lr] = wv.w;
        __syncthreads();
        #pragma unroll
        for (int k = 0; k < 16; ++k) {
            float a0 = Xs[k][tr * 4 + 0], a1 = Xs[k][tr * 4 + 1];
            float a2 = Xs[k][tr * 4 + 2], a3 = Xs[k][tr * 4 + 3];
            float b0 = Ws[k][tc * 4 + 0], b1 = Ws[k][tc * 4 + 1];
            float b2 = Ws[k][tc * 4 + 2], b3 = Ws[k][tc * 4 + 3];
            acc[0][0] = fmaf(a0, b0, acc[0][0]); acc[0][1] = fmaf(a0, b1, acc[0][1]);
            acc[0][2] = fmaf(a0, b2, acc[0][2]); acc[0][3] = fmaf(a0, b3, acc[0][3]);
            acc[1][0] = fmaf(a1, b0, acc[1][0]); acc[1][1] = fmaf(a1, b1, acc[1][1]);
            acc[1][2] = fmaf(a1, b2, acc[1][2]); acc[1][3] = fmaf(a1, b3, acc[1][3]);
            acc[2][0] = fmaf(a2, b0, acc[2][0]); acc[2][1] = fmaf(a2, b1, acc[2][1]);
            acc[2][2] = fmaf(a2, b2, acc[2][2]); acc[2][3] = fmaf(a2, b3, acc[2][3]);
            acc[3][0] = fmaf(a3, b0, acc[3][0]); acc[3][1] = fmaf(a3, b1, acc[3][1]);
            acc[3][2] = fmaf(a3, b2, acc[3][2]); acc[3][3] = fmaf(a3, b3, acc[3][3]);
        }
        __syncthreads();
    }
    #pragma unroll
    for (int i = 0; i < 4; ++i) {
        int row = bm + tr * 4 + i;
        #pragma unroll
        for (int j = 0; j < 4; ++j) {
            int col = bn + tc * 4 + j;
            if (col < nrows) Y[(size_t)row * ldY + col] = acc[i][j];
        }
    }
}

// ---------------- per-token head logsumexp ----------------
__global__ __launch_bounds__(256) void head_lse_kernel(
    const float* __restrict__ H, const int* __restrict__ target,
    float* __restrict__ a0, float* __restrict__ a1, float* __restrict__ out)
{
    const int t = blockIdx.x;
    const int tid = threadIdx.x;
    const float* row = H + (size_t)t * DIM;
    __shared__ float red[256];
    float m = -1e30f;
    for (int j = tid; j < NHEAD; j += 256) m = fmaxf(m, row[j]);
    red[tid] = m;
    __syncthreads();
    for (int off = 128; off; off >>= 1) {
        if (tid < off) red[tid] = fmaxf(red[tid], red[tid + off]);
        __syncthreads();
    }
    float M = red[0];
    __syncthreads();
    float s = 0.f;
    for (int j = tid; j < NHEAD; j += 256) s += __expf(row[j] - M);
    red[tid] = s;
    __syncthreads();
    for (int off = 128; off; off >>= 1) {
        if (tid < off) red[tid] += red[tid + off];
        __syncthreads();
    }
    if (tid == 0) {
        float lse = M + __logf(red[0]);
        a0[t] = row[1000] - lse;
        a1[t] = row[1001] - lse;
        int tg = target[t];
        if (tg < NSHORT) out[t] = row[tg] - lse;
    }
}

// ---------------- cluster exp-sum via MFMA (flash-style, no-max trick) ----
// Block = 4 waves; wave w handles 16 tokens (list idx blockIdx.x*64+w*16 ..).
// Class dim split over blockIdx.y in units of 16-class tiles.
// Logits |v| <~ 1, so sum exp(v) directly in fp32 — no running max needed.
template<int K>
__global__ __launch_bounds__(256) void cluster_flash(
    const unsigned short* __restrict__ XAh, const unsigned short* __restrict__ Wbh,
    int C, const int* __restrict__ list, const int* __restrict__ cnt, int ci,
    int tilesPerStripe, float* __restrict__ psum)
{
    constexpr int NCH = K / 32;
    const int n = cnt[ci];
    const int wv = threadIdx.x >> 6;
    const int lane = threadIdx.x & 63;
    const int gbase = blockIdx.x * 64 + wv * 16;
    if (gbase >= n) return;
    const int m = lane & 15, q = lane >> 4;
    int iTok = gbase + m;
    int tok = list[(iTok < n) ? iTok : (n - 1)];
    // A fragments: A[m=token][k=q*8+j+c*32], contiguous 8 bf16 per lane
    short8 a[NCH];
    const unsigned short* ap = XAh + (size_t)tok * K + q * 8;
    #pragma unroll
    for (int c = 0; c < NCH; ++c) a[c] = *(const short8*)(ap + c * 32);

    const int sp = blockIdx.y;
    const int nTiles = (C + 15) / 16;
    int t0 = sp * tilesPerStripe;
    int t1 = min(t0 + tilesPerStripe, nTiles);

    float s0 = 0.f, s1 = 0.f, s2 = 0.f, s3 = 0.f;
    for (int T = t0; T < t1; ++T) {
        int j = T * 16 + m;                       // class for this lane (col)
        int jc = (j < C) ? j : (C - 1);
        const unsigned short* bp = Wbh + (size_t)jc * K + q * 8;
        float4v acc = {0.f, 0.f, 0.f, 0.f};
        #pragma unroll
        for (int c = 0; c < NCH; ++c) {
            short8 b = *(const short8*)(bp + c * 32);
            acc = __builtin_amdgcn_mfma_f32_16x16x32_bf16(a[c], b, acc, 0, 0, 0);
        }
        if (j < C) {
            s0 += __expf(acc[0]);
            s1 += __expf(acc[1]);
            s2 += __expf(acc[2]);
            s3 += __expf(acc[3]);
        }
    }
    // reduce across the 16 class-lanes of each quad
    #pragma unroll
    for (int off = 1; off < 16; off <<= 1) {
        s0 += __shfl_xor(s0, off, 64);
        s1 += __shfl_xor(s1, off, 64);
        s2 += __shfl_xor(s2, off, 64);
        s3 += __shfl_xor(s3, off, 64);
    }
    if (m == 0) {
        // C/D layout: row = q*4 + reg  -> list index gbase + q*4 + reg
        int r0 = gbase + q * 4;
        if (r0 + 0 < n) psum[(size_t)(r0 + 0) * PS + sp] = s0;
        if (r0 + 1 < n) psum[(size_t)(r0 + 1) * PS + sp] = s1;
        if (r0 + 2 < n) psum[(size_t)(r0 + 2) * PS + sp] = s2;
        if (r0 + 3 < n) psum[(size_t)(r0 + 3) * PS + sp] = s3;
    }
}

// ---------------- fp32 target logit: one wave per listed token ------------
template<int K>
__global__ __launch_bounds__(256) void tgt_dot(
    const float* __restrict__ XA, const float* __restrict__ Wb, int base,
    const int* __restrict__ list, const int* __restrict__ cnt, int ci,
    const int* __restrict__ target, float* __restrict__ tgtlog)
{
    const int n = cnt[ci];
    int i = blockIdx.x * 4 + (threadIdx.x >> 6);
    if (i >= n) return;
    int lane = threadIdx.x & 63;
    int tok = list[i];
    int tg = target[tok] - base;
    const float* xp = XA + (size_t)tok * K;
    const float* wp = Wb + (size_t)tg * K;
    float s = 0.f;
    #pragma unroll
    for (int k = lane; k < K; k += 64) s += xp[k] * wp[k];
    #pragma unroll
    for (int off = 32; off; off >>= 1) s += __shfl_xor(s, off, 64);
    if (lane == 0) tgtlog[tok] = s;
}

// ---------------- combine split exp-sums -> output ----------------
__global__ __launch_bounds__(256) void combine_kernel(
    const int* __restrict__ cnt, int ci, const int* __restrict__ list,
    const float* __restrict__ psum, int splits,
    const float* __restrict__ tgtlog, const float* __restrict__ gate,
    float* __restrict__ out)
{
    int i = blockIdx.x * 256 + threadIdx.x;
    if (i >= cnt[ci]) return;
    int tok = list[i];
    float S = 0.f;
    for (int sp = 0; sp < splits; ++sp) S += psum[(size_t)i * PS + sp];
    out[tok] = tgtlog[tok] - logf(S) + gate[tok];
}

// ---------------- loss = -mean(out) ----------------
__global__ __launch_bounds__(256) void loss_kernel(
    const float* __restrict__ out, float* __restrict__ loss)
{
    __shared__ float red[256];
    int tid = threadIdx.x;
    float s = 0.f;
    for (int j = tid; j < TOK; j += 256) s += out[j];
    red[tid] = s;
    __syncthreads();
    for (int off = 128; off; off >>= 1) {
        if (tid < off) red[tid] += red[tid + off];
        __syncthreads();
    }
    if (tid == 0) loss[0] = -red[0] / (float)TOK;
}

extern "C" void kernel_launch(void* const* d_in, const int* in_sizes, int n_in,
                              void* d_out, int out_size, void* d_ws, size_t ws_size,
                              hipStream_t stream) {
    const float* x      = (const float*)d_in[0];
    const int*   target = (const int*)  d_in[1];
    const float* W_head = (const float*)d_in[2];
    const float* W0a    = (const float*)d_in[3];
    const float* W0b    = (const float*)d_in[4];
    const float* W1a    = (const float*)d_in[5];
    const float* W1b    = (const float*)d_in[6];
    float* out  = (float*)d_out;
    float* loss = out + TOK;

    // workspace layout
    float* ws     = (float*)d_ws;
    float* H      = ws;                              // TOK*1024
    float* XA0    = H + (size_t)TOK * 1024;          // TOK*256
    float* XA1    = XA0 + (size_t)TOK * K0;          // TOK*64
    float* a0     = XA1 + (size_t)TOK * K1;          // TOK
    float* a1     = a0 + TOK;                        // TOK
    float* tgtlog = a1 + TOK;                        // TOK
    float* psum0  = tgtlog + TOK;                    // TOK*PS
    float* psum1  = psum0 + (size_t)TOK * PS;        // TOK*PS
    unsigned short* W0bh = (unsigned short*)(psum1 + (size_t)TOK * PS); // C0*K0
    unsigned short* W1bh = W0bh + (size_t)C0 * K0;   // C1*K1
    unsigned short* XA0h = W1bh + (size_t)C1 * K1;   // TOK*K0
    unsigned short* XA1h = XA0h + (size_t)TOK * K0;  // TOK*K1
    int* cnt = (int*)(XA1h + (size_t)TOK * K1);
    int* l0  = cnt + 8;
    int* l1  = l0 + TOK;

    zero_kernel<<<1, 64, 0, stream>>>(cnt);
    classify_kernel<<<TOK / 256, 256, 0, stream>>>(target, cnt, l0, l1);

    // fp32 GEMMs
    sgemm_xwT<<<dim3((NHEAD + 63) / 64, TOK / 64), 256, 0, stream>>>(x, W_head, H, NHEAD, 1024);
    sgemm_xwT<<<dim3(K0 / 64, TOK / 64), 256, 0, stream>>>(x, W0a, XA0, K0, K0);
    sgemm_xwT<<<dim3(K1 / 64, TOK / 64), 256, 0, stream>>>(x, W1a, XA1, K1, K1);

    // bf16 casts for MFMA operands
    cast_bf16_kernel<<<(C0 * K0 + 255) / 256, 256, 0, stream>>>(W0b, W0bh, C0 * K0);
    cast_bf16_kernel<<<(C1 * K1 + 255) / 256, 256, 0, stream>>>(W1b, W1bh, C1 * K1);
    cast_bf16_kernel<<<(TOK * K0 + 255) / 256, 256, 0, stream>>>(XA0, XA0h, TOK * K0);
    cast_bf16_kernel<<<(TOK * K1 + 255) / 256, 256, 0, stream>>>(XA1, XA1h, TOK * K1);

    head_lse_kernel<<<TOK, 256, 0, stream>>>(H, target, a0, a1, out);

    // MFMA flash exp-sums
    {
        int tiles0 = (C0 + 15) / 16;                       // 563
        int tps0 = (tiles0 + SP0 - 1) / SP0;               // 36
        cluster_flash<K0><<<dim3(TOK / 64, SP0), 256, 0, stream>>>(
            XA0h, W0bh, C0, l0, cnt, 0, tps0, psum0);
        int tiles1 = (C1 + 15) / 16;                       // 2517
        int tps1 = (tiles1 + SP1 - 1) / SP1;               // 79
        cluster_flash<K1><<<dim3(TOK / 64, SP1), 256, 0, stream>>>(
            XA1h, W1bh, C1, l1, cnt, 1, tps1, psum1);
    }

    // exact fp32 target logits
    tgt_dot<K0><<<TOK / 4, 256, 0, stream>>>(XA0, W0b, NSHORT, l0, cnt, 0, target, tgtlog);
    tgt_dot<K1><<<TOK / 4, 256, 0, stream>>>(XA1, W1b, NSHORT + C0, l1, cnt, 1, target, tgtlog);

    combine_kernel<<<TOK / 256, 256, 0, stream>>>(cnt, 0, l0, psum0, SP0, tgtlog, a0, out);
    combine_kernel<<<TOK / 256, 256, 0, stream>>>(cnt, 1, l1, psum1, SP1, tgtlog, a1, out);

    loss_kernel<<<1, 256, 0, stream>>>(out, loss);
}

// Round 3
// 315.454 us; speedup vs baseline: 5.0003x; 2.0977x over previous
//
#include <hip/hip_runtime.h>
#include <math.h>

#define TOK    4096
#define DIM    1024
#define NHEAD  1002
#define NSHORT 1000
#define C0     9000
#define K0     256
#define C1     40257
#define K1     64
#define SP0    64
#define SP1    32
#define PS     64    // psum row stride (>= max splits)

typedef __attribute__((ext_vector_type(8))) short short8;
typedef __attribute__((ext_vector_type(4))) float float4v;

__device__ __forceinline__ void gld_lds16(const void* g, void* l) {
    __builtin_amdgcn_global_load_lds(
        (const __attribute__((address_space(1))) unsigned int*)g,
        (__attribute__((address_space(3))) unsigned int*)l,
        16, 0, 0);
}

__device__ __forceinline__ unsigned short f2bf(float f) {
    unsigned int u = __float_as_uint(f);
    return (unsigned short)((u + 0x7FFFu + ((u >> 16) & 1u)) >> 16);
}

// ---------------- zero counters ----------------
__global__ void zero_kernel(int* cnt) {
    if (threadIdx.x < 2) cnt[threadIdx.x] = 0;
}

// ---------------- classify targets into cluster lists ----------------
__global__ __launch_bounds__(256) void classify_kernel(
    const int* __restrict__ target, int* __restrict__ cnt,
    int* __restrict__ l0, int* __restrict__ l1)
{
    int t = blockIdx.x * 256 + threadIdx.x;
    if (t >= TOK) return;
    int tg = target[t];
    if (tg >= NSHORT && tg < NSHORT + C0) {
        int i = atomicAdd(&cnt[0], 1); l0[i] = t;
    } else if (tg >= NSHORT + C0) {
        int i = atomicAdd(&cnt[1], 1); l1[i] = t;
    }
}

// ---------------- fp32 -> bf16 cast, 4 elems/thread ----------------
__global__ __launch_bounds__(256) void cast_bf16_kernel(
    const float* __restrict__ src, unsigned short* __restrict__ dst, int n4)
{
    int i = blockIdx.x * 256 + threadIdx.x;
    if (i < n4) {
        float4 v = ((const float4*)src)[i];
        ushort4 o;
        o.x = f2bf(v.x); o.y = f2bf(v.y); o.z = f2bf(v.z); o.w = f2bf(v.w);
        ((ushort4*)dst)[i] = o;
    }
}

// ---------------- bf16 MFMA GEMM: Y = Ah @ Bh^T ----------------
// Ah: (TOK, DIM); Bh: (nrows, DIM); Y fp32 (TOK, ldY); Yh optional bf16 (TOK, ldh).
// Block 256 = 4 waves; BM=64 (wave w -> rows w*16..), BN=64, BK=64, dbuf LDS.
// LDS chunk layout = MFMA fragment order: chunk = 16 rows x 32 k, lane -> (row=lane&15, k8=lane>>4).
__global__ __launch_bounds__(256) void gemm_bf16(
    const unsigned short* __restrict__ Ah, const unsigned short* __restrict__ Bh,
    float* __restrict__ Y, unsigned short* __restrict__ Yh,
    int nrows, int ldY, int ldh)
{
    __shared__ short ldsA[2][4096];   // 8 chunks x 512 shorts per buffer
    __shared__ short ldsB[2][4096];
    const int tid = threadIdx.x, wv = tid >> 6, lane = tid & 63;
    const int nn = lane & 15, c8 = lane >> 4;
    const int bm = blockIdx.y * 64, bn = blockIdx.x * 64;
    float4v acc[4];
    #pragma unroll
    for (int c = 0; c < 4; ++c) acc[c] = (float4v){0.f, 0.f, 0.f, 0.f};

    auto stage = [&](int b, int kk) {
        #pragma unroll
        for (int i = 0; i < 4; ++i) {
            int ch = wv * 4 + i;
            if (ch < 8) {             // A chunks: rowgroup rg, k-half kc
                int rg = ch >> 1, kc = ch & 1;
                int row = bm + rg * 16 + nn;
                const unsigned short* gp = Ah + (size_t)row * DIM + kk + kc * 32 + c8 * 8;
                gld_lds16(gp, &ldsA[b][ch * 512]);
            } else {                  // B chunks: colgroup cg, k-half kc
                int bc = ch - 8, cg = bc >> 1, kc = bc & 1;
                int row = bn + cg * 16 + nn;
                if (row > nrows - 1) row = nrows - 1;
                const unsigned short* gp = Bh + (size_t)row * DIM + kk + kc * 32 + c8 * 8;
                gld_lds16(gp, &ldsB[b][bc * 512]);
            }
        }
    };

    int buf = 0;
    stage(0, 0);
    __syncthreads();
    for (int s = 0; s < DIM / 64; ++s) {
        if (s + 1 < DIM / 64) stage(buf ^ 1, (s + 1) * 64);
        short8 a0 = *(const short8*)&ldsA[buf][(wv * 2 + 0) * 512 + lane * 8];
        short8 a1 = *(const short8*)&ldsA[buf][(wv * 2 + 1) * 512 + lane * 8];
        #pragma unroll
        for (int c = 0; c < 4; ++c) {
            short8 b0 = *(const short8*)&ldsB[buf][(c * 2 + 0) * 512 + lane * 8];
            short8 b1 = *(const short8*)&ldsB[buf][(c * 2 + 1) * 512 + lane * 8];
            acc[c] = __builtin_amdgcn_mfma_f32_16x16x32_bf16(a0, b0, acc[c], 0, 0, 0);
            acc[c] = __builtin_amdgcn_mfma_f32_16x16x32_bf16(a1, b1, acc[c], 0, 0, 0);
        }
        __syncthreads();
        buf ^= 1;
    }
    // C/D layout: col = lane&15, row(within wave tile) = (lane>>4)*4 + r
    #pragma unroll
    for (int c = 0; c < 4; ++c) {
        int col = bn + c * 16 + nn;
        if (col < nrows) {
            #pragma unroll
            for (int r = 0; r < 4; ++r) {
                int row = bm + wv * 16 + c8 * 4 + r;
                Y[(size_t)row * ldY + col] = acc[c][r];
                if (Yh) Yh[(size_t)row * ldh + col] = f2bf(acc[c][r]);
            }
        }
    }
}

// ---------------- per-token head logsumexp ----------------
__global__ __launch_bounds__(256) void head_lse_kernel(
    const float* __restrict__ H, const int* __restrict__ target,
    float* __restrict__ a0, float* __restrict__ a1, float* __restrict__ out)
{
    const int t = blockIdx.x;
    const int tid = threadIdx.x;
    const float* row = H + (size_t)t * DIM;
    __shared__ float red[256];
    float m = -1e30f;
    for (int j = tid; j < NHEAD; j += 256) m = fmaxf(m, row[j]);
    red[tid] = m;
    __syncthreads();
    for (int off = 128; off; off >>= 1) {
        if (tid < off) red[tid] = fmaxf(red[tid], red[tid + off]);
        __syncthreads();
    }
    float M = red[0];
    __syncthreads();
    float s = 0.f;
    for (int j = tid; j < NHEAD; j += 256) s += __expf(row[j] - M);
    red[tid] = s;
    __syncthreads();
    for (int off = 128; off; off >>= 1) {
        if (tid < off) red[tid] += red[tid + off];
        __syncthreads();
    }
    if (tid == 0) {
        float lse = M + __logf(red[0]);
        a0[t] = row[1000] - lse;
        a1[t] = row[1001] - lse;
        int tg = target[t];
        if (tg < NSHORT) out[t] = row[tg] - lse;
    }
}

// ---------------- cluster exp-sum: LDS-staged MFMA GEMM + exp epilogue ----
// Block = 128 tokens (4 waves x 2 m-tiles of 16). Classes: stripe of 16-class
// ctiles per blockIdx.y. B staged via global_load_lds (dbuf, 16KB each),
// shared by all 4 waves; fragment reads are conflict-free ds_read_b128.
// Logits |v| <~ 1 -> plain sum of exp in fp32, no running max.
template<int K>
__global__ __launch_bounds__(256) void cluster_lse2(
    const unsigned short* __restrict__ XAh, const unsigned short* __restrict__ Wbh,
    int C, const int* __restrict__ list, const int* __restrict__ cnt, int ci,
    int tps, float* __restrict__ psum)
{
    constexpr int NCH = K / 32;        // 1KB k-chunks (and MFMAs) per ctile
    constexpr int G   = 16 / NCH;      // ctiles per LDS buffer (16 chunks)
    const int n = cnt[ci];
    if ((int)blockIdx.x * 128 >= n) return;   // uniform whole-block exit
    __shared__ short lds[2][8192];     // 2 x 16 KB
    const int tid = threadIdx.x, wv = tid >> 6, lane = tid & 63;
    const int m = lane & 15, q = lane >> 4;
    const int nT = (C + 15) / 16;
    const int T0 = blockIdx.y * tps;
    const int T1 = min(T0 + tps, nT);

    // A fragments for 2 token-tiles
    short8 a[2][NCH];
    #pragma unroll
    for (int t = 0; t < 2; ++t) {
        int iTok = blockIdx.x * 128 + t * 64 + wv * 16 + m;
        int tok = list[(iTok < n) ? iTok : (n - 1)];
        const unsigned short* ap = XAh + (size_t)tok * K + q * 8;
        #pragma unroll
        for (int kc = 0; kc < NCH; ++kc) a[t][kc] = *(const short8*)(ap + kc * 32);
    }

    float s[2][4] = {};

    auto stage = [&](int b, int Tb) {
        #pragma unroll
        for (int i = 0; i < 4; ++i) {
            int ch = wv * 4 + i;
            int g = ch / NCH, kc = ch % NCH;
            int row = (Tb + g) * 16 + m;
            if (row > C - 1) row = C - 1;
            const unsigned short* gp = Wbh + (size_t)row * K + kc * 32 + q * 8;
            gld_lds16(gp, &lds[b][ch * 512]);
        }
    };

    int buf = 0;
    stage(0, T0);
    __syncthreads();
    for (int Tb = T0; Tb < T1; Tb += G) {
        if (Tb + G < T1) stage(buf ^ 1, Tb + G);
        #pragma unroll
        for (int g = 0; g < G; ++g) {
            if (Tb + g < T1) {
                float4v acc0 = {0.f, 0.f, 0.f, 0.f};
                float4v acc1 = {0.f, 0.f, 0.f, 0.f};
                #pragma unroll
                for (int kc = 0; kc < NCH; ++kc) {
                    short8 bfr = *(const short8*)&lds[buf][(g * NCH + kc) * 512 + lane * 8];
                    acc0 = __builtin_amdgcn_mfma_f32_16x16x32_bf16(a[0][kc], bfr, acc0, 0, 0, 0);
                    acc1 = __builtin_amdgcn_mfma_f32_16x16x32_bf16(a[1][kc], bfr, acc1, 0, 0, 0);
                }
                int j = (Tb + g) * 16 + m;   // class column of this lane
                if (j < C) {
                    #pragma unroll
                    for (int r = 0; r < 4; ++r) {
                        s[0][r] += __expf(acc0[r]);
                        s[1][r] += __expf(acc1[r]);
                    }
                }
            }
        }
        __syncthreads();
        buf ^= 1;
    }
    // reduce across 16 class lanes
    #pragma unroll
    for (int off = 1; off < 16; off <<= 1) {
        #pragma unroll
        for (int t = 0; t < 2; ++t)
            #pragma unroll
            for (int r = 0; r < 4; ++r)
                s[t][r] += __shfl_xor(s[t][r], off, 64);
    }
    if (m == 0) {
        #pragma unroll
        for (int t = 0; t < 2; ++t)
            #pragma unroll
            for (int r = 0; r < 4; ++r) {
                int r0 = blockIdx.x * 128 + t * 64 + wv * 16 + q * 4 + r;
                if (r0 < n) psum[(size_t)r0 * PS + blockIdx.y] = s[t][r];
            }
    }
}

// ---------------- fp32 target logit: one wave per listed token ------------
template<int K>
__global__ __launch_bounds__(256) void tgt_dot(
    const float* __restrict__ XA, const float* __restrict__ Wb, int base,
    const int* __restrict__ list, const int* __restrict__ cnt, int ci,
    const int* __restrict__ target, float* __restrict__ tgtlog)
{
    const int n = cnt[ci];
    int i = blockIdx.x * 4 + (threadIdx.x >> 6);
    if (i >= n) return;
    int lane = threadIdx.x & 63;
    int tok = list[i];
    int tg = target[tok] - base;
    const float* xp = XA + (size_t)tok * K;
    const float* wp = Wb + (size_t)tg * K;
    float s = 0.f;
    #pragma unroll
    for (int k = lane; k < K; k += 64) s += xp[k] * wp[k];
    #pragma unroll
    for (int off = 32; off; off >>= 1) s += __shfl_xor(s, off, 64);
    if (lane == 0) tgtlog[tok] = s;
}

// ---------------- combine split exp-sums -> output ----------------
__global__ __launch_bounds__(256) void combine_kernel(
    const int* __restrict__ cnt, int ci, const int* __restrict__ list,
    const float* __restrict__ psum, int splits,
    const float* __restrict__ tgtlog, const float* __restrict__ gate,
    float* __restrict__ out)
{
    int i = blockIdx.x * 256 + threadIdx.x;
    if (i >= cnt[ci]) return;
    int tok = list[i];
    float S = 0.f;
    for (int sp = 0; sp < splits; ++sp) S += psum[(size_t)i * PS + sp];
    out[tok] = tgtlog[tok] - logf(S) + gate[tok];
}

// ---------------- loss = -mean(out) ----------------
__global__ __launch_bounds__(256) void loss_kernel(
    const float* __restrict__ out, float* __restrict__ loss)
{
    __shared__ float red[256];
    int tid = threadIdx.x;
    float s = 0.f;
    for (int j = tid; j < TOK; j += 256) s += out[j];
    red[tid] = s;
    __syncthreads();
    for (int off = 128; off; off >>= 1) {
        if (tid < off) red[tid] += red[tid + off];
        __syncthreads();
    }
    if (tid == 0) loss[0] = -red[0] / (float)TOK;
}

extern "C" void kernel_launch(void* const* d_in, const int* in_sizes, int n_in,
                              void* d_out, int out_size, void* d_ws, size_t ws_size,
                              hipStream_t stream) {
    const float* x      = (const float*)d_in[0];
    const int*   target = (const int*)  d_in[1];
    const float* W_head = (const float*)d_in[2];
    const float* W0a    = (const float*)d_in[3];
    const float* W0b    = (const float*)d_in[4];
    const float* W1a    = (const float*)d_in[5];
    const float* W1b    = (const float*)d_in[6];
    float* out  = (float*)d_out;
    float* loss = out + TOK;

    // workspace layout (16B alignment maintained for all bf16 arrays)
    float* ws     = (float*)d_ws;
    float* H      = ws;                               // 4096*1024
    float* XA0    = H + (size_t)TOK * 1024;           // 4096*256
    float* XA1    = XA0 + (size_t)TOK * K0;           // 4096*64
    float* a0     = XA1 + (size_t)TOK * K1;           // 4096
    float* a1     = a0 + TOK;
    float* tgtlog = a1 + TOK;
    float* psum0  = tgtlog + TOK;                     // 4096*64
    float* psum1  = psum0 + (size_t)TOK * PS;         // 4096*64
    unsigned short* xh     = (unsigned short*)(psum1 + (size_t)TOK * PS);
    unsigned short* Wheadh = xh + (size_t)TOK * DIM;        // 1002*1024
    unsigned short* W0ah   = Wheadh + (size_t)NHEAD * DIM;  // 256*1024
    unsigned short* W0bh   = W0ah + (size_t)K0 * DIM;       // 9000*256
    unsigned short* W1ah   = W0bh + (size_t)C0 * K0;        // 64*1024
    unsigned short* W1bh   = W1ah + (size_t)K1 * DIM;       // 40257*64
    unsigned short* XA0h   = W1bh + (size_t)C1 * K1;        // 4096*256
    unsigned short* XA1h   = XA0h + (size_t)TOK * K0;       // 4096*64
    int* cnt = (int*)(XA1h + (size_t)TOK * K1);
    int* l0  = cnt + 8;
    int* l1  = l0 + TOK;

    zero_kernel<<<1, 64, 0, stream>>>(cnt);
    classify_kernel<<<TOK / 256, 256, 0, stream>>>(target, cnt, l0, l1);

    // bf16 casts (all sizes divisible by 4)
    cast_bf16_kernel<<<(TOK * DIM / 4 + 255) / 256, 256, 0, stream>>>(x, xh, TOK * DIM / 4);
    cast_bf16_kernel<<<(NHEAD * DIM / 4 + 255) / 256, 256, 0, stream>>>(W_head, Wheadh, NHEAD * DIM / 4);
    cast_bf16_kernel<<<(K0 * DIM / 4 + 255) / 256, 256, 0, stream>>>(W0a, W0ah, K0 * DIM / 4);
    cast_bf16_kernel<<<(C0 * K0 / 4 + 255) / 256, 256, 0, stream>>>(W0b, W0bh, C0 * K0 / 4);
    cast_bf16_kernel<<<(K1 * DIM / 4 + 255) / 256, 256, 0, stream>>>(W1a, W1ah, K1 * DIM / 4);
    cast_bf16_kernel<<<(C1 * K1 / 4 + 255) / 256, 256, 0, stream>>>(W1b, W1bh, C1 * K1 / 4);

    // MFMA GEMMs: H (fp32 only), XA0/XA1 (fp32 + bf16)
    gemm_bf16<<<dim3((NHEAD + 63) / 64, TOK / 64), 256, 0, stream>>>(xh, Wheadh, H, (unsigned short*)nullptr, NHEAD, 1024, 0);
    gemm_bf16<<<dim3(K0 / 64, TOK / 64), 256, 0, stream>>>(xh, W0ah, XA0, XA0h, K0, K0, K0);
    gemm_bf16<<<dim3(K1 / 64, TOK / 64), 256, 0, stream>>>(xh, W1ah, XA1, XA1h, K1, K1, K1);

    head_lse_kernel<<<TOK, 256, 0, stream>>>(H, target, a0, a1, out);

    // cluster exp-sums
    {
        int nT0 = (C0 + 15) / 16;                  // 563
        int tps0 = (nT0 + SP0 - 1) / SP0;          // 9
        cluster_lse2<K0><<<dim3(TOK / 128, SP0), 256, 0, stream>>>(
            XA0h, W0bh, C0, l0, cnt, 0, tps0, psum0);
        int nT1 = (C1 + 15) / 16;                  // 2517
        int tps1 = (nT1 + SP1 - 1) / SP1;          // 79
        cluster_lse2<K1><<<dim3(TOK / 128, SP1), 256, 0, stream>>>(
            XA1h, W1bh, C1, l1, cnt, 1, tps1, psum1);
    }

    // exact fp32 target logits
    tgt_dot<K0><<<TOK / 4, 256, 0, stream>>>(XA0, W0b, NSHORT, l0, cnt, 0, target, tgtlog);
    tgt_dot<K1><<<TOK / 4, 256, 0, stream>>>(XA1, W1b, NSHORT + C0, l1, cnt, 1, target, tgtlog);

    combine_kernel<<<TOK / 256, 256, 0, stream>>>(cnt, 0, l0, psum0, SP0, tgtlog, a0, out);
    combine_kernel<<<TOK / 256, 256, 0, stream>>>(cnt, 1, l1, psum1, SP1, tgtlog, a1, out);

    loss_kernel<<<1, 256, 0, stream>>>(out, loss);
}

// Round 4
// 269.585 us; speedup vs baseline: 5.8511x; 1.1701x over previous
//
#include <hip/hip_runtime.h>
#include <math.h>

#define TOK    4096
#define DIM    1024
#define NHEAD  1002
#define NSHORT 1000
#define C0     9000
#define K0     256
#define C1     40257
#define K1     64
#define SP0    64
#define SP1    64
#define PS     64

typedef __attribute__((ext_vector_type(8))) short short8;
typedef __attribute__((ext_vector_type(4))) float float4v;

__device__ __forceinline__ void gld_lds16(const void* g, void* l) {
    __builtin_amdgcn_global_load_lds(
        (const __attribute__((address_space(1))) unsigned int*)g,
        (__attribute__((address_space(3))) unsigned int*)l,
        16, 0, 0);
}

__device__ __forceinline__ unsigned short f2bf(float f) {
    unsigned int u = __float_as_uint(f);
    return (unsigned short)((u + 0x7FFFu + ((u >> 16) & 1u)) >> 16);
}

// ---------------- classify targets into cluster lists ----------------
__global__ __launch_bounds__(256) void classify_kernel(
    const int* __restrict__ target, int* __restrict__ cnt,
    int* __restrict__ l0, int* __restrict__ l1)
{
    int t = blockIdx.x * 256 + threadIdx.x;
    if (t >= TOK) return;
    int tg = target[t];
    if (tg >= NSHORT && tg < NSHORT + C0) {
        int i = atomicAdd(&cnt[0], 1); l0[i] = t;
    } else if (tg >= NSHORT + C0) {
        int i = atomicAdd(&cnt[1], 1); l1[i] = t;
    }
}

// ---------------- all fp32->bf16 casts in ONE launch (+ cnt zeroing) ------
// Segment offsets in float4 units (compile-time).
#define S0E (TOK * DIM / 4)                 // x        1048576
#define S1E (S0E + NHEAD * DIM / 4)         // W_head   +256512
#define S2E (S1E + K0 * DIM / 4)            // W0a      +65536
#define S3E (S2E + C0 * K0 / 4)             // W0b      +576000
#define S4E (S3E + K1 * DIM / 4)            // W1a      +16384
#define S5E (S4E + C1 * K1 / 4)             // W1b      +644112  -> 2607120
__global__ __launch_bounds__(256) void megacast_kernel(
    const float* __restrict__ x, const float* __restrict__ W_head,
    const float* __restrict__ W0a, const float* __restrict__ W0b,
    const float* __restrict__ W1a, const float* __restrict__ W1b,
    unsigned short* __restrict__ xh, unsigned short* __restrict__ Wheadh,
    unsigned short* __restrict__ W0ah, unsigned short* __restrict__ W0bh,
    unsigned short* __restrict__ W1ah, unsigned short* __restrict__ W1bh,
    int* __restrict__ cnt)
{
    int i = blockIdx.x * 256 + threadIdx.x;
    if (i == 0) { cnt[0] = 0; cnt[1] = 0; }
    const float* src; unsigned short* dst; int off;
    if      (i < S0E) { src = x;      dst = xh;     off = i; }
    else if (i < S1E) { src = W_head; dst = Wheadh; off = i - S0E; }
    else if (i < S2E) { src = W0a;    dst = W0ah;   off = i - S1E; }
    else if (i < S3E) { src = W0b;    dst = W0bh;   off = i - S2E; }
    else if (i < S4E) { src = W1a;    dst = W1ah;   off = i - S3E; }
    else if (i < S5E) { src = W1b;    dst = W1bh;   off = i - S4E; }
    else return;
    float4 v = ((const float4*)src)[off];
    ushort4 o;
    o.x = f2bf(v.x); o.y = f2bf(v.y); o.z = f2bf(v.z); o.w = f2bf(v.w);
    ((ushort4*)dst)[off] = o;
}

// ---------------- fused bf16 MFMA GEMMs: H, XA0, XA1 in one launch --------
// blockIdx.x: [0,16) head tiles, [16,20) XA0 tiles, [20] XA1. blockIdx.y: row tile.
// BM=64 (wave w -> rows w*16..), BN=64, BK=64, dbuf LDS via global_load_lds.
__global__ __launch_bounds__(256) void gemm_fused(
    const unsigned short* __restrict__ Ah,
    const unsigned short* __restrict__ Wheadh, const unsigned short* __restrict__ W0ah,
    const unsigned short* __restrict__ W1ah,
    float* __restrict__ H, float* __restrict__ XA0, float* __restrict__ XA1,
    unsigned short* __restrict__ XA0h, unsigned short* __restrict__ XA1h)
{
    const unsigned short* Bh; float* Y; unsigned short* Yh; int nrows, ldY, bn;
    if (blockIdx.x < 16)      { Bh = Wheadh; Y = H;   Yh = nullptr; nrows = NHEAD; ldY = 1024; bn = blockIdx.x * 64; }
    else if (blockIdx.x < 20) { Bh = W0ah;   Y = XA0; Yh = XA0h;    nrows = K0;    ldY = K0;   bn = (blockIdx.x - 16) * 64; }
    else                      { Bh = W1ah;   Y = XA1; Yh = XA1h;    nrows = K1;    ldY = K1;   bn = 0; }

    __shared__ short ldsA[2][4096];
    __shared__ short ldsB[2][4096];
    const int tid = threadIdx.x, wv = tid >> 6, lane = tid & 63;
    const int nn = lane & 15, c8 = lane >> 4;
    const int bm = blockIdx.y * 64;
    float4v acc[4];
    #pragma unroll
    for (int c = 0; c < 4; ++c) acc[c] = (float4v){0.f, 0.f, 0.f, 0.f};

    auto stage = [&](int b, int kk) {
        #pragma unroll
        for (int i = 0; i < 4; ++i) {
            int ch = wv * 4 + i;
            if (ch < 8) {
                int rg = ch >> 1, kc = ch & 1;
                int row = bm + rg * 16 + nn;
                gld_lds16(Ah + (size_t)row * DIM + kk + kc * 32 + c8 * 8, &ldsA[b][ch * 512]);
            } else {
                int bc = ch - 8, cg = bc >> 1, kc = bc & 1;
                int row = bn + cg * 16 + nn;
                if (row > nrows - 1) row = nrows - 1;
                gld_lds16(Bh + (size_t)row * DIM + kk + kc * 32 + c8 * 8, &ldsB[b][bc * 512]);
            }
        }
    };

    int buf = 0;
    stage(0, 0);
    __syncthreads();
    for (int s = 0; s < DIM / 64; ++s) {
        if (s + 1 < DIM / 64) stage(buf ^ 1, (s + 1) * 64);
        short8 a0 = *(const short8*)&ldsA[buf][(wv * 2 + 0) * 512 + lane * 8];
        short8 a1 = *(const short8*)&ldsA[buf][(wv * 2 + 1) * 512 + lane * 8];
        #pragma unroll
        for (int c = 0; c < 4; ++c) {
            short8 b0 = *(const short8*)&ldsB[buf][(c * 2 + 0) * 512 + lane * 8];
            short8 b1 = *(const short8*)&ldsB[buf][(c * 2 + 1) * 512 + lane * 8];
            acc[c] = __builtin_amdgcn_mfma_f32_16x16x32_bf16(a0, b0, acc[c], 0, 0, 0);
            acc[c] = __builtin_amdgcn_mfma_f32_16x16x32_bf16(a1, b1, acc[c], 0, 0, 0);
        }
        __syncthreads();
        buf ^= 1;
    }
    #pragma unroll
    for (int c = 0; c < 4; ++c) {
        int col = bn + c * 16 + nn;
        if (col < nrows) {
            #pragma unroll
            for (int r = 0; r < 4; ++r) {
                int row = bm + wv * 16 + c8 * 4 + r;
                Y[(size_t)row * ldY + col] = acc[c][r];
                if (Yh) Yh[(size_t)row * ldY + col] = f2bf(acc[c][r]);
            }
        }
    }
}

// ---------------- per-token head logsumexp ----------------
__global__ __launch_bounds__(256) void head_lse_kernel(
    const float* __restrict__ H, const int* __restrict__ target,
    float* __restrict__ a0, float* __restrict__ a1, float* __restrict__ out)
{
    const int t = blockIdx.x;
    const int tid = threadIdx.x;
    const float* row = H + (size_t)t * DIM;
    __shared__ float red[256];
    float m = -1e30f;
    for (int j = tid; j < NHEAD; j += 256) m = fmaxf(m, row[j]);
    red[tid] = m;
    __syncthreads();
    for (int off = 128; off; off >>= 1) {
        if (tid < off) red[tid] = fmaxf(red[tid], red[tid + off]);
        __syncthreads();
    }
    float M = red[0];
    __syncthreads();
    float s = 0.f;
    for (int j = tid; j < NHEAD; j += 256) s += __expf(row[j] - M);
    red[tid] = s;
    __syncthreads();
    for (int off = 128; off; off >>= 1) {
        if (tid < off) red[tid] += red[tid + off];
        __syncthreads();
    }
    if (tid == 0) {
        float lse = M + __logf(red[0]);
        a0[t] = row[1000] - lse;
        a1[t] = row[1001] - lse;
        int tg = target[t];
        if (tg < NSHORT) out[t] = row[tg] - lse;
    }
}

// ---------------- cluster exp-sum: LDS-staged MFMA GEMM + exp epilogue ----
// Block = 128 tokens (4 waves x 2 m-tiles). G ctiles per LDS buffer.
// K=64: G=4 -> 2x8KB LDS (8 blocks/CU). K=256: G=2 -> 2x16KB.
template<int K, int G>
__global__ __launch_bounds__(256) void cluster_lse2(
    const unsigned short* __restrict__ XAh, const unsigned short* __restrict__ Wbh,
    int C, const int* __restrict__ list, const int* __restrict__ cnt, int ci,
    int tps, float* __restrict__ psum)
{
    constexpr int NCH = K / 32;
    constexpr int CPB = G * NCH;          // chunks (1KB) per buffer
    const int n = cnt[ci];
    if ((int)blockIdx.x * 128 >= n) return;
    __shared__ short lds[2][CPB * 512];
    const int tid = threadIdx.x, wv = tid >> 6, lane = tid & 63;
    const int m = lane & 15, q = lane >> 4;
    const int nT = (C + 15) / 16;
    const int T0 = blockIdx.y * tps;
    const int T1 = min(T0 + tps, nT);
    if (T0 >= nT) return;

    short8 a[2][NCH];
    #pragma unroll
    for (int t = 0; t < 2; ++t) {
        int iTok = blockIdx.x * 128 + t * 64 + wv * 16 + m;
        int tok = list[(iTok < n) ? iTok : (n - 1)];
        const unsigned short* ap = XAh + (size_t)tok * K + q * 8;
        #pragma unroll
        for (int kc = 0; kc < NCH; ++kc) a[t][kc] = *(const short8*)(ap + kc * 32);
    }

    float s[2][4] = {};

    auto stage = [&](int b, int Tb) {
        #pragma unroll
        for (int i = 0; i < CPB / 4; ++i) {
            int ch = wv * (CPB / 4) + i;
            int g = ch / NCH, kc = ch % NCH;
            int row = (Tb + g) * 16 + m;
            if (row > C - 1) row = C - 1;
            gld_lds16(Wbh + (size_t)row * K + kc * 32 + q * 8, &lds[b][ch * 512]);
        }
    };

    int buf = 0;
    stage(0, T0);
    __syncthreads();
    for (int Tb = T0; Tb < T1; Tb += G) {
        if (Tb + G < T1) stage(buf ^ 1, Tb + G);
        #pragma unroll
        for (int g = 0; g < G; ++g) {
            if (Tb + g < T1) {
                float4v acc0 = {0.f, 0.f, 0.f, 0.f};
                float4v acc1 = {0.f, 0.f, 0.f, 0.f};
                #pragma unroll
                for (int kc = 0; kc < NCH; ++kc) {
                    short8 bfr = *(const short8*)&lds[buf][(g * NCH + kc) * 512 + lane * 8];
                    acc0 = __builtin_amdgcn_mfma_f32_16x16x32_bf16(a[0][kc], bfr, acc0, 0, 0, 0);
                    acc1 = __builtin_amdgcn_mfma_f32_16x16x32_bf16(a[1][kc], bfr, acc1, 0, 0, 0);
                }
                int j = (Tb + g) * 16 + m;
                if (j < C) {
                    #pragma unroll
                    for (int r = 0; r < 4; ++r) {
                        s[0][r] += __expf(acc0[r]);
                        s[1][r] += __expf(acc1[r]);
                    }
                }
            }
        }
        __syncthreads();
        buf ^= 1;
    }
    #pragma unroll
    for (int off = 1; off < 16; off <<= 1) {
        #pragma unroll
        for (int t = 0; t < 2; ++t)
            #pragma unroll
            for (int r = 0; r < 4; ++r)
                s[t][r] += __shfl_xor(s[t][r], off, 64);
    }
    if (m == 0) {
        #pragma unroll
        for (int t = 0; t < 2; ++t)
            #pragma unroll
            for (int r = 0; r < 4; ++r) {
                int r0 = blockIdx.x * 128 + t * 64 + wv * 16 + q * 4 + r;
                if (r0 < n) psum[(size_t)r0 * PS + blockIdx.y] = s[t][r];
            }
    }
}

// ---------------- fused: fp32 target dot + psum-sum + gate -> out ---------
// One wave per listed token; blockIdx.y = cluster id.
__global__ __launch_bounds__(256) void tgt_combine_kernel(
    const float* __restrict__ XA0, const float* __restrict__ W0b,
    const float* __restrict__ XA1, const float* __restrict__ W1b,
    const int* __restrict__ l0, const int* __restrict__ l1,
    const int* __restrict__ cnt, const int* __restrict__ target,
    const float* __restrict__ psum0, const float* __restrict__ psum1,
    const float* __restrict__ a0, const float* __restrict__ a1,
    int tps0, int tps1, float* __restrict__ out)
{
    const int ci = blockIdx.y;
    const int n = cnt[ci];
    int i = blockIdx.x * 4 + (threadIdx.x >> 6);
    if (i >= n) return;
    int lane = threadIdx.x & 63;
    const int* list = ci ? l1 : l0;
    int tok = list[i];
    float dot, S;
    if (ci == 0) {
        int tg = target[tok] - NSHORT;
        const float* xp = XA0 + (size_t)tok * K0;
        const float* wp = W0b + (size_t)tg * K0;
        float s = 0.f;
        #pragma unroll
        for (int k = 0; k < K0 / 64; ++k) s += xp[lane + k * 64] * wp[lane + k * 64];
        dot = s;
        int nT = (C0 + 15) / 16;
        S = (lane * tps0 < nT) ? psum0[(size_t)i * PS + lane] : 0.f;
    } else {
        int tg = target[tok] - (NSHORT + C0);
        dot = XA1[(size_t)tok * K1 + lane] * W1b[(size_t)tg * K1 + lane];
        int nT = (C1 + 15) / 16;
        S = (lane * tps1 < nT) ? psum1[(size_t)i * PS + lane] : 0.f;
    }
    #pragma unroll
    for (int off = 32; off; off >>= 1) {
        dot += __shfl_xor(dot, off, 64);
        S += __shfl_xor(S, off, 64);
    }
    if (lane == 0) out[tok] = dot - logf(S) + (ci ? a1[tok] : a0[tok]);
}

// ---------------- loss = -mean(out) ----------------
__global__ __launch_bounds__(256) void loss_kernel(
    const float* __restrict__ out, float* __restrict__ loss)
{
    __shared__ float red[256];
    int tid = threadIdx.x;
    float s = 0.f;
    for (int j = tid; j < TOK; j += 256) s += out[j];
    red[tid] = s;
    __syncthreads();
    for (int off = 128; off; off >>= 1) {
        if (tid < off) red[tid] += red[tid + off];
        __syncthreads();
    }
    if (tid == 0) loss[0] = -red[0] / (float)TOK;
}

extern "C" void kernel_launch(void* const* d_in, const int* in_sizes, int n_in,
                              void* d_out, int out_size, void* d_ws, size_t ws_size,
                              hipStream_t stream) {
    const float* x      = (const float*)d_in[0];
    const int*   target = (const int*)  d_in[1];
    const float* W_head = (const float*)d_in[2];
    const float* W0a    = (const float*)d_in[3];
    const float* W0b    = (const float*)d_in[4];
    const float* W1a    = (const float*)d_in[5];
    const float* W1b    = (const float*)d_in[6];
    float* out  = (float*)d_out;
    float* loss = out + TOK;

    float* ws     = (float*)d_ws;
    float* H      = ws;                               // 4096*1024
    float* XA0    = H + (size_t)TOK * 1024;           // 4096*256
    float* XA1    = XA0 + (size_t)TOK * K0;           // 4096*64
    float* a0     = XA1 + (size_t)TOK * K1;           // 4096
    float* a1     = a0 + TOK;
    float* tgtlog = a1 + TOK;                         // (unused, kept for layout)
    float* psum0  = tgtlog + TOK;                     // 4096*64
    float* psum1  = psum0 + (size_t)TOK * PS;         // 4096*64
    unsigned short* xh     = (unsigned short*)(psum1 + (size_t)TOK * PS);
    unsigned short* Wheadh = xh + (size_t)TOK * DIM;
    unsigned short* W0ah   = Wheadh + (size_t)NHEAD * DIM;
    unsigned short* W0bh   = W0ah + (size_t)K0 * DIM;
    unsigned short* W1ah   = W0bh + (size_t)C0 * K0;
    unsigned short* W1bh   = W1ah + (size_t)K1 * DIM;
    unsigned short* XA0h   = W1bh + (size_t)C1 * K1;
    unsigned short* XA1h   = XA0h + (size_t)TOK * K0;
    int* cnt = (int*)(XA1h + (size_t)TOK * K1);
    int* l0  = cnt + 8;
    int* l1  = l0 + TOK;

    megacast_kernel<<<(S5E + 255) / 256, 256, 0, stream>>>(
        x, W_head, W0a, W0b, W1a, W1b, xh, Wheadh, W0ah, W0bh, W1ah, W1bh, cnt);
    classify_kernel<<<TOK / 256, 256, 0, stream>>>(target, cnt, l0, l1);

    gemm_fused<<<dim3(21, TOK / 64), 256, 0, stream>>>(
        xh, Wheadh, W0ah, W1ah, H, XA0, XA1, XA0h, XA1h);

    head_lse_kernel<<<TOK, 256, 0, stream>>>(H, target, a0, a1, out);

    int nT0 = (C0 + 15) / 16;                  // 563
    int tps0 = (nT0 + SP0 - 1) / SP0;          // 9
    cluster_lse2<K0, 2><<<dim3(TOK / 128, SP0), 256, 0, stream>>>(
        XA0h, W0bh, C0, l0, cnt, 0, tps0, psum0);
    int nT1 = (C1 + 15) / 16;                  // 2517
    int tps1 = (nT1 + SP1 - 1) / SP1;          // 40
    cluster_lse2<K1, 4><<<dim3(TOK / 128, SP1), 256, 0, stream>>>(
        XA1h, W1bh, C1, l1, cnt, 1, tps1, psum1);

    tgt_combine_kernel<<<dim3(TOK / 4, 2), 256, 0, stream>>>(
        XA0, W0b, XA1, W1b, l0, l1, cnt, target, psum0, psum1, a0, a1, tps0, tps1, out);

    loss_kernel<<<1, 256, 0, stream>>>(out, loss);
}

// Round 5
// 257.956 us; speedup vs baseline: 6.1149x; 1.0451x over previous
//
#include <hip/hip_runtime.h>
#include <math.h>

#define TOK    4096
#define DIM    1024
#define NHEAD  1002
#define NSHORT 1000
#define C0     9000
#define K0     256
#define C1     40257
#define K1     64
#define SP0    64
#define SP1    64
#define PS     64

typedef __attribute__((ext_vector_type(8))) short short8;
typedef __attribute__((ext_vector_type(4))) float float4v;

__device__ __forceinline__ void gld_lds16(const void* g, void* l) {
    __builtin_amdgcn_global_load_lds(
        (const __attribute__((address_space(1))) unsigned int*)g,
        (__attribute__((address_space(3))) unsigned int*)l,
        16, 0, 0);
}

__device__ __forceinline__ unsigned short f2bf(float f) {
    unsigned int u = __float_as_uint(f);
    return (unsigned short)((u + 0x7FFFu + ((u >> 16) & 1u)) >> 16);
}

// ---------------- classify targets into cluster lists ----------------
__global__ __launch_bounds__(256) void classify_kernel(
    const int* __restrict__ target, int* __restrict__ cnt,
    int* __restrict__ l0, int* __restrict__ l1)
{
    int t = blockIdx.x * 256 + threadIdx.x;
    if (t >= TOK) return;
    int tg = target[t];
    if (tg >= NSHORT && tg < NSHORT + C0) {
        int i = atomicAdd(&cnt[0], 1); l0[i] = t;
    } else if (tg >= NSHORT + C0) {
        int i = atomicAdd(&cnt[1], 1); l1[i] = t;
    }
}

// ---------------- all fp32->bf16 casts in ONE launch (+ zero init) --------
#define S0E (TOK * DIM / 4)
#define S1E (S0E + NHEAD * DIM / 4)
#define S2E (S1E + K0 * DIM / 4)
#define S3E (S2E + C0 * K0 / 4)
#define S4E (S3E + K1 * DIM / 4)
#define S5E (S4E + C1 * K1 / 4)
__global__ __launch_bounds__(256) void megacast_kernel(
    const float* __restrict__ x, const float* __restrict__ W_head,
    const float* __restrict__ W0a, const float* __restrict__ W0b,
    const float* __restrict__ W1a, const float* __restrict__ W1b,
    unsigned short* __restrict__ xh, unsigned short* __restrict__ Wheadh,
    unsigned short* __restrict__ W0ah, unsigned short* __restrict__ W0bh,
    unsigned short* __restrict__ W1ah, unsigned short* __restrict__ W1bh,
    int* __restrict__ cnt, float* __restrict__ Shead)
{
    int i = blockIdx.x * 256 + threadIdx.x;
    if (i == 0) { cnt[0] = 0; cnt[1] = 0; }
    if (i < TOK / 4) ((float4*)Shead)[i] = (float4){0.f, 0.f, 0.f, 0.f};
    const float* src; unsigned short* dst; int off;
    if      (i < S0E) { src = x;      dst = xh;     off = i; }
    else if (i < S1E) { src = W_head; dst = Wheadh; off = i - S0E; }
    else if (i < S2E) { src = W0a;    dst = W0ah;   off = i - S1E; }
    else if (i < S3E) { src = W0b;    dst = W0bh;   off = i - S2E; }
    else if (i < S4E) { src = W1a;    dst = W1ah;   off = i - S3E; }
    else if (i < S5E) { src = W1b;    dst = W1bh;   off = i - S4E; }
    else return;
    float4 v = ((const float4*)src)[off];
    ushort4 o;
    o.x = f2bf(v.x); o.y = f2bf(v.y); o.z = f2bf(v.z); o.w = f2bf(v.w);
    ((ushort4*)dst)[off] = o;
}

// ---------------- 128x128x64 bf16 MFMA GEMM, head-softmax-fused ----------
// blockIdx.x: [0,8) head col-tiles (exp-sum epilogue, H never stored),
//             [8,10) XA0, [10] XA1 (store fp32+bf16). blockIdx.y: 128-row tile.
// 4 waves in 2x2; wave computes 64x64 = 4x4 16x16 MFMA tiles.
// LDS: A,B 128x64 bf16 chunked in fragment order, double buffered (64 KB).
__global__ __launch_bounds__(256, 2) void gemm128(
    const unsigned short* __restrict__ Ah,
    const unsigned short* __restrict__ Wheadh, const unsigned short* __restrict__ W0ah,
    const unsigned short* __restrict__ W1ah,
    const int* __restrict__ target,
    float* __restrict__ Shead, float* __restrict__ g0, float* __restrict__ g1,
    float* __restrict__ th,
    float* __restrict__ XA0, float* __restrict__ XA1,
    unsigned short* __restrict__ XA0h, unsigned short* __restrict__ XA1h)
{
    const int bx = blockIdx.x;
    const unsigned short* Bh; int nrows, bn, seg, ldY;
    float* Y; unsigned short* Yh;
    if (bx < 8)       { seg = 0; Bh = Wheadh; nrows = NHEAD; bn = bx * 128;       Y = nullptr; Yh = nullptr; ldY = 0; }
    else if (bx < 10) { seg = 1; Bh = W0ah;   nrows = K0;    bn = (bx - 8) * 128; Y = XA0;     Yh = XA0h;    ldY = K0; }
    else              { seg = 2; Bh = W1ah;   nrows = K1;    bn = 0;              Y = XA1;     Yh = XA1h;    ldY = K1; }
    const int bm = blockIdx.y * 128;

    __shared__ short ldsA[2][8192];   // 16 chunks x 512 shorts
    __shared__ short ldsB[2][8192];
    const int tid = threadIdx.x, wv = tid >> 6, lane = tid & 63;
    const int nn = lane & 15, q = lane >> 4;
    const int wr = wv >> 1, wc = wv & 1;

    float4v acc[4][4];
    #pragma unroll
    for (int i = 0; i < 4; ++i)
        #pragma unroll
        for (int j = 0; j < 4; ++j) acc[i][j] = (float4v){0.f, 0.f, 0.f, 0.f};

    auto stage = [&](int b, int kk) {
        #pragma unroll
        for (int i2 = 0; i2 < 8; ++i2) {
            if (wv < 2) {
                int ch = wv * 8 + i2, rg = ch >> 1, kc = ch & 1;
                int row = bm + rg * 16 + nn;
                gld_lds16(Ah + (size_t)row * DIM + kk + kc * 32 + q * 8, &ldsA[b][ch * 512]);
            } else {
                int ch = (wv - 2) * 8 + i2, rg = ch >> 1, kc = ch & 1;
                int row = bn + rg * 16 + nn;
                if (row > nrows - 1) row = nrows - 1;
                gld_lds16(Bh + (size_t)row * DIM + kk + kc * 32 + q * 8, &ldsB[b][ch * 512]);
            }
        }
    };

    int buf = 0;
    stage(0, 0);
    __syncthreads();
    for (int s = 0; s < DIM / 64; ++s) {
        if (s + 1 < DIM / 64) stage(buf ^ 1, (s + 1) * 64);
        short8 afr[4][2], bfr[4][2];
        #pragma unroll
        for (int i = 0; i < 4; ++i)
            #pragma unroll
            for (int kc = 0; kc < 2; ++kc)
                afr[i][kc] = *(const short8*)&ldsA[buf][((wr * 4 + i) * 2 + kc) * 512 + lane * 8];
        #pragma unroll
        for (int j = 0; j < 4; ++j)
            #pragma unroll
            for (int kc = 0; kc < 2; ++kc)
                bfr[j][kc] = *(const short8*)&ldsB[buf][((wc * 4 + j) * 2 + kc) * 512 + lane * 8];
        #pragma unroll
        for (int kc = 0; kc < 2; ++kc)
            #pragma unroll
            for (int i = 0; i < 4; ++i)
                #pragma unroll
                for (int j = 0; j < 4; ++j)
                    acc[i][j] = __builtin_amdgcn_mfma_f32_16x16x32_bf16(afr[i][kc], bfr[j][kc], acc[i][j], 0, 0, 0);
        __syncthreads();
        buf ^= 1;
    }

    if (seg == 0) {
        // head: per-row partial exp-sum + gate/target logit capture
        #pragma unroll
        for (int i = 0; i < 4; ++i) {
            int rowr[4], tg[4];
            float s[4] = {0.f, 0.f, 0.f, 0.f};
            #pragma unroll
            for (int r = 0; r < 4; ++r) {
                rowr[r] = bm + wr * 64 + i * 16 + q * 4 + r;
                tg[r] = target[rowr[r]];
            }
            #pragma unroll
            for (int j = 0; j < 4; ++j) {
                int col = bn + wc * 64 + j * 16 + nn;
                bool cv = (col < NHEAD);
                #pragma unroll
                for (int r = 0; r < 4; ++r) {
                    float v = acc[i][j][r];
                    if (cv) {
                        s[r] += __expf(v);
                        if (col == 1000) g0[rowr[r]] = v;
                        if (col == 1001) g1[rowr[r]] = v;
                        if (tg[r] < NSHORT && col == tg[r]) th[rowr[r]] = v;
                    }
                }
            }
            #pragma unroll
            for (int off = 1; off < 16; off <<= 1)
                #pragma unroll
                for (int r = 0; r < 4; ++r) s[r] += __shfl_xor(s[r], off, 64);
            if (nn == 0) {
                #pragma unroll
                for (int r = 0; r < 4; ++r) atomicAdd(&Shead[rowr[r]], s[r]);
            }
        }
    } else {
        #pragma unroll
        for (int i = 0; i < 4; ++i)
            #pragma unroll
            for (int j = 0; j < 4; ++j) {
                int col = bn + wc * 64 + j * 16 + nn;
                if (col < nrows) {
                    #pragma unroll
                    for (int r = 0; r < 4; ++r) {
                        int row = bm + wr * 64 + i * 16 + q * 4 + r;
                        float v = acc[i][j][r];
                        Y[(size_t)row * ldY + col] = v;
                        Yh[(size_t)row * ldY + col] = f2bf(v);
                    }
                }
            }
    }
}

// ---------------- head finish: lse, gates, shortlist outputs --------------
__global__ __launch_bounds__(256) void head_finish_kernel(
    const float* __restrict__ Shead, const float* __restrict__ g0,
    const float* __restrict__ g1, const float* __restrict__ th,
    const int* __restrict__ target,
    float* __restrict__ a0, float* __restrict__ a1, float* __restrict__ out)
{
    int t = blockIdx.x * 256 + threadIdx.x;
    if (t >= TOK) return;
    float lse = logf(Shead[t]);
    a0[t] = g0[t] - lse;
    a1[t] = g1[t] - lse;
    int tg = target[t];
    if (tg < NSHORT) out[t] = th[t] - lse;
}

// ---------------- cluster exp-sum: LDS-staged MFMA GEMM + exp epilogue ----
template<int K, int G>
__global__ __launch_bounds__(256) void cluster_lse2(
    const unsigned short* __restrict__ XAh, const unsigned short* __restrict__ Wbh,
    int C, const int* __restrict__ list, const int* __restrict__ cnt, int ci,
    int tps, float* __restrict__ psum)
{
    constexpr int NCH = K / 32;
    constexpr int CPB = G * NCH;
    const int n = cnt[ci];
    if ((int)blockIdx.x * 128 >= n) return;
    __shared__ short lds[2][CPB * 512];
    const int tid = threadIdx.x, wv = tid >> 6, lane = tid & 63;
    const int m = lane & 15, q = lane >> 4;
    const int nT = (C + 15) / 16;
    const int T0 = blockIdx.y * tps;
    const int T1 = min(T0 + tps, nT);
    if (T0 >= nT) return;

    short8 a[2][NCH];
    #pragma unroll
    for (int t = 0; t < 2; ++t) {
        int iTok = blockIdx.x * 128 + t * 64 + wv * 16 + m;
        int tok = list[(iTok < n) ? iTok : (n - 1)];
        const unsigned short* ap = XAh + (size_t)tok * K + q * 8;
        #pragma unroll
        for (int kc = 0; kc < NCH; ++kc) a[t][kc] = *(const short8*)(ap + kc * 32);
    }

    float s[2][4] = {};

    auto stage = [&](int b, int Tb) {
        #pragma unroll
        for (int i = 0; i < CPB / 4; ++i) {
            int ch = wv * (CPB / 4) + i;
            int g = ch / NCH, kc = ch % NCH;
            int row = (Tb + g) * 16 + m;
            if (row > C - 1) row = C - 1;
            gld_lds16(Wbh + (size_t)row * K + kc * 32 + q * 8, &lds[b][ch * 512]);
        }
    };

    int buf = 0;
    stage(0, T0);
    __syncthreads();
    for (int Tb = T0; Tb < T1; Tb += G) {
        if (Tb + G < T1) stage(buf ^ 1, Tb + G);
        #pragma unroll
        for (int g = 0; g < G; ++g) {
            if (Tb + g < T1) {
                float4v acc0 = {0.f, 0.f, 0.f, 0.f};
                float4v acc1 = {0.f, 0.f, 0.f, 0.f};
                #pragma unroll
                for (int kc = 0; kc < NCH; ++kc) {
                    short8 bfr = *(const short8*)&lds[buf][(g * NCH + kc) * 512 + lane * 8];
                    acc0 = __builtin_amdgcn_mfma_f32_16x16x32_bf16(a[0][kc], bfr, acc0, 0, 0, 0);
                    acc1 = __builtin_amdgcn_mfma_f32_16x16x32_bf16(a[1][kc], bfr, acc1, 0, 0, 0);
                }
                int j = (Tb + g) * 16 + m;
                if (j < C) {
                    #pragma unroll
                    for (int r = 0; r < 4; ++r) {
                        s[0][r] += __expf(acc0[r]);
                        s[1][r] += __expf(acc1[r]);
                    }
                }
            }
        }
        __syncthreads();
        buf ^= 1;
    }
    #pragma unroll
    for (int off = 1; off < 16; off <<= 1) {
        #pragma unroll
        for (int t = 0; t < 2; ++t)
            #pragma unroll
            for (int r = 0; r < 4; ++r)
                s[t][r] += __shfl_xor(s[t][r], off, 64);
    }
    if (m == 0) {
        #pragma unroll
        for (int t = 0; t < 2; ++t)
            #pragma unroll
            for (int r = 0; r < 4; ++r) {
                int r0 = blockIdx.x * 128 + t * 64 + wv * 16 + q * 4 + r;
                if (r0 < n) psum[(size_t)r0 * PS + blockIdx.y] = s[t][r];
            }
    }
}

// ---------------- fused: fp32 target dot + psum-sum + gate -> out ---------
__global__ __launch_bounds__(256) void tgt_combine_kernel(
    const float* __restrict__ XA0, const float* __restrict__ W0b,
    const float* __restrict__ XA1, const float* __restrict__ W1b,
    const int* __restrict__ l0, const int* __restrict__ l1,
    const int* __restrict__ cnt, const int* __restrict__ target,
    const float* __restrict__ psum0, const float* __restrict__ psum1,
    const float* __restrict__ a0, const float* __restrict__ a1,
    int tps0, int tps1, float* __restrict__ out)
{
    const int ci = blockIdx.y;
    const int n = cnt[ci];
    int i = blockIdx.x * 4 + (threadIdx.x >> 6);
    if (i >= n) return;
    int lane = threadIdx.x & 63;
    const int* list = ci ? l1 : l0;
    int tok = list[i];
    float dot, S;
    if (ci == 0) {
        int tg = target[tok] - NSHORT;
        const float* xp = XA0 + (size_t)tok * K0;
        const float* wp = W0b + (size_t)tg * K0;
        float s = 0.f;
        #pragma unroll
        for (int k = 0; k < K0 / 64; ++k) s += xp[lane + k * 64] * wp[lane + k * 64];
        dot = s;
        int nT = (C0 + 15) / 16;
        S = (lane * tps0 < nT) ? psum0[(size_t)i * PS + lane] : 0.f;
    } else {
        int tg = target[tok] - (NSHORT + C0);
        dot = XA1[(size_t)tok * K1 + lane] * W1b[(size_t)tg * K1 + lane];
        int nT = (C1 + 15) / 16;
        S = (lane * tps1 < nT) ? psum1[(size_t)i * PS + lane] : 0.f;
    }
    #pragma unroll
    for (int off = 32; off; off >>= 1) {
        dot += __shfl_xor(dot, off, 64);
        S += __shfl_xor(S, off, 64);
    }
    if (lane == 0) out[tok] = dot - logf(S) + (ci ? a1[tok] : a0[tok]);
}

// ---------------- loss = -mean(out) ----------------
__global__ __launch_bounds__(256) void loss_kernel(
    const float* __restrict__ out, float* __restrict__ loss)
{
    __shared__ float red[256];
    int tid = threadIdx.x;
    float s = 0.f;
    for (int j = tid; j < TOK; j += 256) s += out[j];
    red[tid] = s;
    __syncthreads();
    for (int off = 128; off; off >>= 1) {
        if (tid < off) red[tid] += red[tid + off];
        __syncthreads();
    }
    if (tid == 0) loss[0] = -red[0] / (float)TOK;
}

extern "C" void kernel_launch(void* const* d_in, const int* in_sizes, int n_in,
                              void* d_out, int out_size, void* d_ws, size_t ws_size,
                              hipStream_t stream) {
    const float* x      = (const float*)d_in[0];
    const int*   target = (const int*)  d_in[1];
    const float* W_head = (const float*)d_in[2];
    const float* W0a    = (const float*)d_in[3];
    const float* W0b    = (const float*)d_in[4];
    const float* W1a    = (const float*)d_in[5];
    const float* W1b    = (const float*)d_in[6];
    float* out  = (float*)d_out;
    float* loss = out + TOK;

    float* ws     = (float*)d_ws;
    float* XA0    = ws;                               // 4096*256
    float* XA1    = XA0 + (size_t)TOK * K0;           // 4096*64
    float* a0     = XA1 + (size_t)TOK * K1;           // 4096
    float* a1     = a0 + TOK;
    float* Shead  = a1 + TOK;                         // 4096
    float* g0     = Shead + TOK;                      // 4096
    float* g1     = g0 + TOK;                         // 4096
    float* th     = g1 + TOK;                         // 4096
    float* psum0  = th + TOK;                         // 4096*64
    float* psum1  = psum0 + (size_t)TOK * PS;         // 4096*64
    unsigned short* xh     = (unsigned short*)(psum1 + (size_t)TOK * PS);
    unsigned short* Wheadh = xh + (size_t)TOK * DIM;
    unsigned short* W0ah   = Wheadh + (size_t)NHEAD * DIM;
    unsigned short* W0bh   = W0ah + (size_t)K0 * DIM;
    unsigned short* W1ah   = W0bh + (size_t)C0 * K0;
    unsigned short* W1bh   = W1ah + (size_t)K1 * DIM;
    unsigned short* XA0h   = W1bh + (size_t)C1 * K1;
    unsigned short* XA1h   = XA0h + (size_t)TOK * K0;
    int* cnt = (int*)(XA1h + (size_t)TOK * K1);
    int* l0  = cnt + 8;
    int* l1  = l0 + TOK;

    megacast_kernel<<<(S5E + 255) / 256, 256, 0, stream>>>(
        x, W_head, W0a, W0b, W1a, W1b, xh, Wheadh, W0ah, W0bh, W1ah, W1bh, cnt, Shead);
    classify_kernel<<<TOK / 256, 256, 0, stream>>>(target, cnt, l0, l1);

    gemm128<<<dim3(11, TOK / 128), 256, 0, stream>>>(
        xh, Wheadh, W0ah, W1ah, target, Shead, g0, g1, th, XA0, XA1, XA0h, XA1h);

    head_finish_kernel<<<TOK / 256, 256, 0, stream>>>(
        Shead, g0, g1, th, target, a0, a1, out);

    int nT0 = (C0 + 15) / 16;                  // 563
    int tps0 = (nT0 + SP0 - 1) / SP0;          // 9
    cluster_lse2<K0, 2><<<dim3(TOK / 128, SP0), 256, 0, stream>>>(
        XA0h, W0bh, C0, l0, cnt, 0, tps0, psum0);
    int nT1 = (C1 + 15) / 16;                  // 2517
    int tps1 = (nT1 + SP1 - 1) / SP1;          // 40
    cluster_lse2<K1, 4><<<dim3(TOK / 128, SP1), 256, 0, stream>>>(
        XA1h, W1bh, C1, l1, cnt, 1, tps1, psum1);

    tgt_combine_kernel<<<dim3(TOK / 4, 2), 256, 0, stream>>>(
        XA0, W0b, XA1, W1b, l0, l1, cnt, target, psum0, psum1, a0, a1, tps0, tps1, out);

    loss_kernel<<<1, 256, 0, stream>>>(out, loss);
}